// Round 9
// baseline (8990.295 us; speedup 1.0000x reference)
//
#include <hip/hip_runtime.h>
#include <math.h>

#define BB 64
#define TT 512
#define FF 512
#define HH 1024
#define NG 4096  // 4H
#define NWG 64   // workgroups = barrier participants

typedef _Float16 half8 __attribute__((ext_vector_type(8)));
typedef float f32x4 __attribute__((ext_vector_type(4)));
typedef unsigned long long u64;

__device__ __forceinline__ float sigm(float x) { return 1.0f / (1.0f + __expf(-x)); }
__device__ __forceinline__ float tanh_fast(float x) {
    x = fminf(fmaxf(x, -30.0f), 30.0f);
    float e = __expf(2.0f * x);
    return (e - 1.0f) / (e + 1.0f);
}

// ---------------------------------------------------------------------------
// x fp32 -> f16, same [B,T,F] layout. 32 MiB into ws.
// ---------------------------------------------------------------------------
__global__ __launch_bounds__(256) void cvt_x(const float* __restrict__ x,
                                             _Float16* __restrict__ x16)
{
    size_t i = ((size_t)blockIdx.x * 256 + threadIdx.x) * 8;
    float4 a = *(const float4*)(x + i);
    float4 b = *(const float4*)(x + i + 4);
    half8 v;
    v[0] = (_Float16)a.x; v[1] = (_Float16)a.y; v[2] = (_Float16)a.z; v[3] = (_Float16)a.w;
    v[4] = (_Float16)b.x; v[5] = (_Float16)b.y; v[6] = (_Float16)b.z; v[7] = (_Float16)b.w;
    *(half8*)(x16 + i) = v;
}

// ---------------------------------------------------------------------------
// Persistent recurrence. 64 wgs x 512 threads (8 waves), 1 block/CU,
// __launch_bounds__(512,1) -> 256-VGPR budget (W frags MUST stay in regs).
// wg owns h-cols [wg*16,+16) -> 64 gemm cols (4 gates x 16).
// Wave w: gate gt = w&3 (= col-tile), row-pair rp = w>>2 (rows [rp*32,+32)).
// W_HH B-frags: 32 half8 = 128 VGPR. W_XH B-frags: 16 half8 = 64 VGPR.
// Per step: stage h (128 KB) -> LDS, 64 h-MFMA + 32 x-MFMA per wave,
// gbuf -> cell update -> sc1 write-through h store.
// Barrier: 64 flags; arrive = 1 relaxed sc1 store; poll = 1 coalesced load
// (lane i watches flags[i]); acquire-inv after poll (tag-only: write-through
// h means no dirty lines; W in regs is immune; x16/BN re-read from LLC).
// h double-buffer lives in d_out (2 * 64*1024 f16 == out_size*4 bytes).
// MODE 0: x16 in ws.  MODE 1: fp32 x inline-cvt (small-ws fallback).
// ---------------------------------------------------------------------------
template<int MODE>
__global__ __launch_bounds__(512, 1) void lstm_rec(
    const float* __restrict__ x, const float* __restrict__ w_xh,
    const float* __restrict__ w_hh, const float* __restrict__ bias,
    const float* __restrict__ scale, const float* __restrict__ offs,
    const float* __restrict__ pmean, const float* __restrict__ pvar,
    const _Float16* __restrict__ x16, int* flags, float* __restrict__ out)
{
    constexpr int HP = 1032;             // hlds pitch (f16): 2064 B, <=2-way banks
    constexpr int GP = 68;               // gbuf pitch (f32)
    extern __shared__ char smem[];
    _Float16* hlds  = (_Float16*)smem;                    // 64*1032*2 = 132096 B
    float*    gbuf  = (float*)(smem + 132096);            // 64*68*4   = 17408 B
    float*    bias_l = (float*)(smem + 132096 + 17408);   // 256 B     -> 149760 total

    const int wg = blockIdx.x, tid = threadIdx.x;
    const int lane = tid & 63, w = tid >> 6;
    const int q = lane >> 4, r = lane & 15;
    const int gt = w & 3;                // gate = col-tile
    const int rp = w >> 2;               // row-pair: rows [rp*32, rp*32+32)
    const int colg = gt * HH + wg * 16 + r;   // this lane's gemm column

    // one-time: B-fragments into VGPRs (fp32 source, scalar gather)
    half8 bh[32];                        // W_HH, K=1024
    #pragma unroll
    for (int kk = 0; kk < 32; ++kk)
        #pragma unroll
        for (int j = 0; j < 8; ++j)
            bh[kk][j] = (_Float16)w_hh[(size_t)(kk * 32 + q * 8 + j) * NG + colg];
    half8 bx[16];                        // W_XH, K=512
    #pragma unroll
    for (int kk = 0; kk < 16; ++kk)
        #pragma unroll
        for (int j = 0; j < 8; ++j)
            bx[kk][j] = (_Float16)w_xh[(size_t)(kk * 32 + q * 8 + j) * NG + colg];

    if (tid < 64) bias_l[tid] = bias[(tid >> 4) * HH + wg * 16 + (tid & 15)];

    _Float16* hbuf = (_Float16*)out;     // buf0=[0,64K) buf1=[64K,128K) f16
    const int m = tid >> 3, cp = (tid & 7) * 2;   // epilogue: (row m, cols cp,cp+1)
    const int c0 = wg * 16 + cp;
    __hip_atomic_store((unsigned*)(hbuf + m * HH + c0), 0u,
                       __ATOMIC_RELAXED, __HIP_MEMORY_SCOPE_AGENT);  // zero buf0

    // step-0 BN params (2 cols/thread)
    float2 mu = *(const float2*)(pmean + c0);
    float2 pv = *(const float2*)(pvar + c0);
    float2 sc = *(const float2*)(scale + c0);
    float2 of = *(const float2*)(offs + c0);

    // x-GEMM for step t: 2 row-tiles, B from bx regs. Independent of h.
    f32x4 xacc0, xacc1;
    auto xgemm = [&](int t) {
        f32x4 a0 = {0, 0, 0, 0}, a1 = {0, 0, 0, 0};
        if constexpr (MODE == 0) {
            const _Float16* xr0 = x16 + ((size_t)(rp * 32 + r) * TT + t) * FF;
            const _Float16* xr1 = x16 + ((size_t)(rp * 32 + 16 + r) * TT + t) * FF;
            #pragma unroll
            for (int kk = 0; kk < 16; ++kk) {
                half8 v0 = *(const half8*)(xr0 + kk * 32 + q * 8);
                half8 v1 = *(const half8*)(xr1 + kk * 32 + q * 8);
                a0 = __builtin_amdgcn_mfma_f32_16x16x32_f16(v0, bx[kk], a0, 0, 0, 0);
                a1 = __builtin_amdgcn_mfma_f32_16x16x32_f16(v1, bx[kk], a1, 0, 0, 0);
            }
        } else {
            const float* xr0 = x + ((size_t)(rp * 32 + r) * TT + t) * FF;
            const float* xr1 = x + ((size_t)(rp * 32 + 16 + r) * TT + t) * FF;
            #pragma unroll
            for (int kk = 0; kk < 16; ++kk) {
                int kb = kk * 32 + q * 8;
                float4 p0 = *(const float4*)(xr0 + kb), p1 = *(const float4*)(xr0 + kb + 4);
                float4 p2 = *(const float4*)(xr1 + kb), p3 = *(const float4*)(xr1 + kb + 4);
                half8 v0, v1;
                v0[0] = (_Float16)p0.x; v0[1] = (_Float16)p0.y; v0[2] = (_Float16)p0.z; v0[3] = (_Float16)p0.w;
                v0[4] = (_Float16)p1.x; v0[5] = (_Float16)p1.y; v0[6] = (_Float16)p1.z; v0[7] = (_Float16)p1.w;
                v1[0] = (_Float16)p2.x; v1[1] = (_Float16)p2.y; v1[2] = (_Float16)p2.z; v1[3] = (_Float16)p2.w;
                v1[4] = (_Float16)p3.x; v1[5] = (_Float16)p3.y; v1[6] = (_Float16)p3.z; v1[7] = (_Float16)p3.w;
                a0 = __builtin_amdgcn_mfma_f32_16x16x32_f16(v0, bx[kk], a0, 0, 0, 0);
                a1 = __builtin_amdgcn_mfma_f32_16x16x32_f16(v1, bx[kk], a1, 0, 0, 0);
            }
        }
        xacc0 = a0; xacc1 = a1;
    };

    int ep = 1;
    __syncthreads();                     // zeros + LDS init drained
    if (tid == 0)
        __hip_atomic_store(&flags[wg], ep, __ATOMIC_RELAXED, __HIP_MEMORY_SCOPE_AGENT);
    xgemm(0);
    if (tid < 64) {
        while (true) {
            int v = __hip_atomic_load(&flags[lane], __ATOMIC_RELAXED, __HIP_MEMORY_SCOPE_AGENT);
            if (__all(v >= ep)) break;
            __builtin_amdgcn_s_sleep(1);
        }
    }
    if (tid == 0) __builtin_amdgcn_fence(__ATOMIC_ACQUIRE, "agent");
    __syncthreads();
    ++ep;

    float2 c01 = {0.0f, 0.0f}, h01 = {0.0f, 0.0f};
    int cur = 0;

    for (int t = 0; t < TT; ++t) {
        // stage h -> LDS (each thread: 256 B contiguous)
        {
            const int seg = tid & 7;
            const _Float16* gs = hbuf + (size_t)cur * (BB * HH) + m * HH + seg * 128;
            _Float16* ld = hlds + m * HP + seg * 128;
            #pragma unroll
            for (int i = 0; i < 16; ++i)
                *(half8*)(ld + i * 8) = *(const half8*)(gs + i * 8);
        }
        __syncthreads();

        // h-GEMM: A from LDS (2 row-tiles), B from bh regs. 64 MFMA/wave.
        f32x4 acc0 = xacc0, acc1 = xacc1;
        const _Float16* ar0 = hlds + (rp * 32 + r) * HP;
        const _Float16* ar1 = hlds + (rp * 32 + 16 + r) * HP;
        #pragma unroll
        for (int kk = 0; kk < 32; ++kk) {
            half8 a0 = *(const half8*)(ar0 + kk * 32 + q * 8);
            half8 a1 = *(const half8*)(ar1 + kk * 32 + q * 8);
            acc0 = __builtin_amdgcn_mfma_f32_16x16x32_f16(a0, bh[kk], acc0, 0, 0, 0);
            acc1 = __builtin_amdgcn_mfma_f32_16x16x32_f16(a1, bh[kk], acc1, 0, 0, 0);
        }

        // C layout: row = q*4+reg (within 16-row tile), col = r
        #pragma unroll
        for (int reg = 0; reg < 4; ++reg) {
            gbuf[(rp * 32 + q * 4 + reg) * GP + gt * 16 + r] = acc0[reg];
            gbuf[(rp * 32 + 16 + q * 4 + reg) * GP + gt * 16 + r] = acc1[reg];
        }
        __syncthreads();

        // cell update: thread (m, cp) owns 2 h-cols
        #pragma unroll
        for (int j = 0; j < 2; ++j) {
            int cl = cp + j;
            float f_ = gbuf[m * GP +  0 + cl] + bias_l[ 0 + cl];
            float i_ = gbuf[m * GP + 16 + cl] + bias_l[16 + cl];
            float o_ = gbuf[m * GP + 32 + cl] + bias_l[32 + cl];
            float g_ = gbuf[m * GP + 48 + cl] + bias_l[48 + cl];
            float cj = (j ? c01.y : c01.x);
            float muj = (j ? mu.y : mu.x), pvj = (j ? pv.y : pv.x);
            float scj = (j ? sc.y : sc.x), ofj = (j ? of.y : of.x);
            cj = sigm(f_ + 1.0f) * cj + sigm(i_) * tanh_fast(g_);
            float cn = (cj - muj) * (scj * rsqrtf(pvj + 1e-5f)) + ofj;
            float hj = sigm(o_) * tanh_fast(cn);
            if (j) { c01.y = cj; h01.y = hj; } else { c01.x = cj; h01.x = hj; }
        }
        if (t < TT - 1) {
            unsigned lo = (unsigned)__builtin_bit_cast(unsigned short, (_Float16)h01.x);
            unsigned hi = (unsigned)__builtin_bit_cast(unsigned short, (_Float16)h01.y);
            __hip_atomic_store((unsigned*)(hbuf + (size_t)(cur ^ 1) * (BB * HH) + m * HH + c0),
                               lo | (hi << 16), __ATOMIC_RELAXED, __HIP_MEMORY_SCOPE_AGENT);
            // prefetch next BN params (h-independent)
            mu = *(const float2*)(pmean + (size_t)(t + 1) * HH + c0);
            pv = *(const float2*)(pvar  + (size_t)(t + 1) * HH + c0);
            sc = *(const float2*)(scale + (size_t)(t + 1) * HH + c0);
            of = *(const float2*)(offs  + (size_t)(t + 1) * HH + c0);
        }

        __syncthreads();   // gbuf reads done; every wave's sc1 h stores drained
        if (tid == 0)
            __hip_atomic_store(&flags[wg], ep, __ATOMIC_RELAXED, __HIP_MEMORY_SCOPE_AGENT);
        if (t + 1 < TT) xgemm(t + 1);    // hidden under flag propagation
        if (tid < 64) {
            while (true) {
                int v = __hip_atomic_load(&flags[lane], __ATOMIC_RELAXED, __HIP_MEMORY_SCOPE_AGENT);
                if (__all(v >= ep)) break;
                __builtin_amdgcn_s_sleep(1);
            }
        }
        if (tid == 0) __builtin_amdgcn_fence(__ATOMIC_ACQUIRE, "agent");
        __syncthreads();
        ++ep;
        cur ^= 1;
    }

    // past the final barrier: nobody reads hbuf again -> fp32 output overwrite
    *(float2*)(out + m * HH + c0) = h01;
}

extern "C" void kernel_launch(void* const* d_in, const int* in_sizes, int n_in,
                              void* d_out, int out_size, void* d_ws, size_t ws_size,
                              hipStream_t stream) {
    const float* x     = (const float*)d_in[0];
    const float* w_xh  = (const float*)d_in[1];
    const float* w_hh  = (const float*)d_in[2];
    const float* bias  = (const float*)d_in[3];
    const float* scale = (const float*)d_in[4];
    const float* offs  = (const float*)d_in[5];
    const float* pmean = (const float*)d_in[6];
    const float* pvar  = (const float*)d_in[7];
    float* out = (float*)d_out;

    int* flags = (int*)d_ws;                          // 256 B
    _Float16* x16 = (_Float16*)((char*)d_ws + 4096);  // 32 MiB
    const size_t X16B = (size_t)BB * TT * FF * 2;
    const int mode = (ws_size >= X16B + 4096) ? 0 : 1;

    (void)hipMemsetAsync(d_ws, 0, 2048, stream);
    if (mode == 0) {
        const size_t nelem = (size_t)BB * TT * FF;
        cvt_x<<<dim3((unsigned)(nelem / (256 * 8))), 256, 0, stream>>>(x, x16);
    }

    const uint32_t shmem = 132096 + 17408 + 256;   // 149760 B
    const void* f = (mode == 0) ? (const void*)&lstm_rec<0>
                                : (const void*)&lstm_rec<1>;
    (void)hipFuncSetAttribute(f, hipFuncAttributeMaxDynamicSharedMemorySize, (int)shmem);

    void* args[] = {&x, &w_xh, &w_hh, &bias, &scale, &offs, &pmean, &pvar,
                    &x16, &flags, &out};
    (void)hipLaunchCooperativeKernel(f, dim3(NWG), dim3(512), args, shmem, stream);
}